// Round 1
// baseline (42588.403 us; speedup 1.0000x reference)
//
#include <hip/hip_runtime.h>

#define BATCH 128
#define SEQN  128
#define NSTEP 255          // 2N-1
#define HDIM  256
#define KDIM  64
#define EDIM  300
#define MDIM  1024
#define COUT  3
#define TWOH  512
#define GC    256          // gates cols (4K)
#define RC    1280         // r_in cols (5H)
#define XK    832          // [bufH | s1H | s2H | h] = 256+256+256+64
#define RK    512          // [s1H | s2H]

#define NWG   256
#define MBLK  512
#define BBR   8            // batch rows per b-block; 16 b-blocks * 8 = 128

// ---- workspace float offsets ----
constexpr size_t OFF_BUFS  = 0;
constexpr size_t SZ_BUFS   = (size_t)BATCH*SEQN*TWOH;          // 8388608
constexpr size_t OFF_STACK = OFF_BUFS + SZ_BUFS;
constexpr size_t SZ_STACK  = (size_t)BATCH*(SEQN+1)*TWOH;      // 8454144
constexpr size_t OFF_GATES = OFF_STACK + SZ_STACK;
constexpr size_t SZ_GATES  = (size_t)2*BATCH*GC;               // double-buffered
constexpr size_t OFF_RIN   = OFF_GATES + SZ_GATES;
constexpr size_t SZ_RIN    = (size_t)BATCH*RC;
constexpr size_t OFF_W1    = OFF_RIN + SZ_RIN;
constexpr size_t SZ_W1     = (size_t)XK*GC;                    // [Wb;Ws1;Ws2;Wl]
constexpr size_t OFF_W2    = OFF_W1 + SZ_W1;
constexpr size_t SZ_W2     = (size_t)RK*RC;                    // [Wright;Wleft]
constexpr size_t OFF_END   = OFF_W2 + SZ_W2;

__device__ __forceinline__ float sigm(float x) { return 1.0f/(1.0f + __expf(-x)); }
__device__ __forceinline__ float tanh_s(float x) {
  float a = fabsf(x);
  float e = __expf(-2.0f*a);
  float t = (1.0f - e)/(1.0f + e);
  return x < 0.0f ? -t : t;
}

// ---------------- pack: concat weights, any_reduce flags, zero barrier ----------------
__global__ __launch_bounds__(256) void pack_kernel(
    const float* __restrict__ Wb, const float* __restrict__ Ws1,
    const float* __restrict__ Ws2, const float* __restrict__ Wl,
    const float* __restrict__ Wleft, const float* __restrict__ Wright,
    const int* __restrict__ trans,
    float* __restrict__ W1c, float* __restrict__ W2c,
    int* __restrict__ anyred, int* __restrict__ cnt)
{
  int gs = gridDim.x * blockDim.x;
  int t0 = blockIdx.x*blockDim.x + threadIdx.x;
  for (int i = t0; i < XK*GC; i += gs) {
    int k = i / GC, j = i - k*GC;
    float v;
    if (k < 256)      v = Wb [(k      )*GC + j];
    else if (k < 512) v = Ws1[(k-256  )*GC + j];
    else if (k < 768) v = Ws2[(k-512  )*GC + j];
    else              v = Wl [(k-768  )*GC + j];
    W1c[i] = v;
  }
  for (int i = t0; i < RK*RC; i += gs) {
    int k = i / RC, j = i - k*RC;
    W2c[i] = (k < 256) ? Wright[k*RC + j] : Wleft[(k-256)*RC + j];
  }
  for (int i = t0; i < NSTEP; i += gs) {
    int any = 0;
    for (int b = 0; b < BATCH; ++b) any |= (trans[b*NSTEP + i] != 0);
    anyred[i] = any;
  }
  if (t0 == 0) *cnt = 0;
}

// ---------------- embedding + projection: bufs[b][n][:] = emb[tok] @ Wproj ----------------
__global__ __launch_bounds__(256) void embed_kernel(
    const int* __restrict__ tokens, const float* __restrict__ emb,
    const float* __restrict__ Wproj, float* __restrict__ bufs)
{
  __shared__ float xe[4][EDIM];
  int r0 = blockIdx.x * 4;
  int tid = threadIdx.x;
  for (int i = tid; i < 4*EDIM; i += 256) {
    int r = i / EDIM, e = i - r*EDIM;
    xe[r][e] = emb[(size_t)tokens[r0 + r]*EDIM + e];
  }
  __syncthreads();
  int c0 = tid*2;
  float a00=0,a01=0,a10=0,a11=0,a20=0,a21=0,a30=0,a31=0;
  for (int e = 0; e < EDIM; ++e) {
    float2 w = *(const float2*)(Wproj + (size_t)e*TWOH + c0);
    float x0 = xe[0][e], x1 = xe[1][e], x2 = xe[2][e], x3 = xe[3][e];
    a00 = fmaf(x0, w.x, a00); a01 = fmaf(x0, w.y, a01);
    a10 = fmaf(x1, w.x, a10); a11 = fmaf(x1, w.y, a11);
    a20 = fmaf(x2, w.x, a20); a21 = fmaf(x2, w.y, a21);
    a30 = fmaf(x3, w.x, a30); a31 = fmaf(x3, w.y, a31);
  }
  float* o;
  o = bufs + (size_t)(r0+0)*TWOH + c0; o[0]=a00; o[1]=a01;
  o = bufs + (size_t)(r0+1)*TWOH + c0; o[0]=a10; o[1]=a11;
  o = bufs + (size_t)(r0+2)*TWOH + c0; o[0]=a20; o[1]=a21;
  o = bufs + (size_t)(r0+3)*TWOH + c0; o[0]=a30; o[1]=a31;
}

// ---------------- persistent main scan ----------------
__device__ __forceinline__ void gbar(int* cnt, int target)
{
  __threadfence();
  __syncthreads();
  if (threadIdx.x == 0) {
    __hip_atomic_fetch_add(cnt, 1, __ATOMIC_RELEASE, __HIP_MEMORY_SCOPE_AGENT);
    while (__hip_atomic_load(cnt, __ATOMIC_ACQUIRE, __HIP_MEMORY_SCOPE_AGENT) < target) {
      __builtin_amdgcn_s_sleep(1);
    }
  }
  __syncthreads();
  __threadfence();
}

__device__ __forceinline__ void lstm_apply(const float* __restrict__ g,
                                           float (*chs)[2*KDIM], int b0, int tid)
{
  for (int it = tid; it < BBR*KDIM; it += MBLK) {
    int r = it >> 6, u = it & 63;
    const float* gr = g + (b0 + r)*GC;
    float cprev = chs[r][u];
    float cc = tanh_s(gr[u])*sigm(gr[64+u]) + sigm(gr[128+u])*cprev;
    chs[r][u] = cc;
    chs[r][KDIM+u] = sigm(gr[192+u])*tanh_s(cc);
  }
}

__global__ __launch_bounds__(MBLK) void spinn_main(
    const int* __restrict__ trans,
    const float* __restrict__ Wtrack,
    const float* __restrict__ bl,
    const float* __restrict__ bred,
    const float* __restrict__ bufs,
    float* __restrict__ stack,
    float* __restrict__ gatesg,
    float* __restrict__ rin,
    const float* __restrict__ W1c,
    const float* __restrict__ W2c,
    const int* __restrict__ anyred,
    int* __restrict__ cnt)
{
  __shared__ __align__(16) float xls[BBR][XK];
  __shared__ float chs[BBR][2*KDIM];     // [r][0:64)=c, [r][64:128)=h
  __shared__ int spb[BBR], bpb[BBR], shf[BBR];
  __shared__ int anyr[NSTEP];

  const int tid = threadIdx.x;
  const int wg  = blockIdx.x;
  const int bb  = wg >> 4;
  const int js  = wg & 15;
  const int b0  = bb * BBR;

  for (int i = tid; i < BBR*2*KDIM; i += MBLK) ((float*)chs)[i] = 0.0f;
  if (tid < BBR) { spb[tid] = 0; bpb[tid] = 0; }
  for (int i = tid; i < NSTEP; i += MBLK) anyr[i] = anyred[i];
  __syncthreads();

  int nbar = 0;
  int pending = 0;

  for (int t = 0; t < NSTEP; ++t) {
    const int red = anyr[t];
    float* gcur        = gatesg + (size_t)(t & 1)*(BATCH*GC);
    const float* gprev = gatesg + (size_t)((t & 1)^1)*(BATCH*GC);

    if (pending) lstm_apply(gprev, chs, b0, tid);   // LSTM of step t-1 (shift step)
    if (tid < BBR) shf[tid] = (trans[(b0+tid)*NSTEP + t] == 0) ? 1 : 0;
    __syncthreads();

    // ---- stage x = [bufH | s1H | s2H | h] into LDS ----
    for (int idx = tid; idx < BBR*HDIM; idx += MBLK) {
      int r = idx >> 8, c = idx & (HDIM-1);
      int b = b0 + r;
      int sp = spb[r], bp = bpb[r];
      int bq = bp < SEQN-1 ? bp : SEQN-1;
      xls[r][c]          = bufs[((size_t)b*SEQN + bq)*TWOH + c];
      xls[r][HDIM + c]   = (sp >= 1) ? stack[((size_t)b*(SEQN+1) + sp-1)*TWOH + c] : 0.0f;
      xls[r][2*HDIM + c] = (sp >= 2) ? stack[((size_t)b*(SEQN+1) + sp-2)*TWOH + c] : 0.0f;
    }
    for (int it = tid; it < BBR*KDIM; it += MBLK) {
      int r = it >> 6, u = it & 63;
      xls[r][3*HDIM + u] = chs[r][KDIM + u];
    }
    __syncthreads();

    // ---- shift-row stack pushes (value is buf_top; no GEMM needed) ----
    if (js == 0) {
      for (int idx = tid; idx < BBR*TWOH; idx += MBLK) {
        int r = idx >> 9, c = idx & (TWOH-1);
        if (shf[r]) {
          int b = b0 + r;
          int bq = bpb[r] < SEQN-1 ? bpb[r] : SEQN-1;
          stack[((size_t)b*(SEQN+1) + spb[r])*TWOH + c] =
              bufs[((size_t)b*SEQN + bq)*TWOH + c];
        }
      }
    }

    // ---- I1 compute: gates (and r_in s-part on reduce steps) ----
    if (red) {
      for (int s = tid; s < 384; s += MBLK) {
        int cl = s % 96, bg = s / 96;
        int col = js*96 + cl;
        const float* xa = &xls[bg][0];
        const float* xb = &xls[bg+4][0];
        if (col < GC) {
          float acc0 = bl[col], acc1 = acc0;
          const float* w = W1c + col;
          const float4* x4a = (const float4*)xa;
          const float4* x4b = (const float4*)xb;
          #pragma unroll 4
          for (int k4 = 0; k4 < XK/4; ++k4) {
            float4 a = x4a[k4], b4 = x4b[k4];
            float w0 = w[0], w1 = w[GC], w2 = w[2*GC], w3 = w[3*GC];
            w += 4*GC;
            acc0 = fmaf(a.x,w0,acc0);  acc0 = fmaf(a.y,w1,acc0);
            acc0 = fmaf(a.z,w2,acc0);  acc0 = fmaf(a.w,w3,acc0);
            acc1 = fmaf(b4.x,w0,acc1); acc1 = fmaf(b4.y,w1,acc1);
            acc1 = fmaf(b4.z,w2,acc1); acc1 = fmaf(b4.w,w3,acc1);
          }
          gcur[(b0+bg  )*GC + col] = acc0;
          gcur[(b0+bg+4)*GC + col] = acc1;
        } else {
          int j = col - GC;
          float acc0 = bred[j], acc1 = acc0;
          const float* w = W2c + j;
          const float4* x4a = (const float4*)(xa + HDIM);   // [s1H | s2H]
          const float4* x4b = (const float4*)(xb + HDIM);
          #pragma unroll 4
          for (int k4 = 0; k4 < RK/4; ++k4) {
            float4 a = x4a[k4], b4 = x4b[k4];
            float w0 = w[0], w1 = w[RC], w2 = w[2*RC], w3 = w[3*RC];
            w += 4*RC;
            acc0 = fmaf(a.x,w0,acc0);  acc0 = fmaf(a.y,w1,acc0);
            acc0 = fmaf(a.z,w2,acc0);  acc0 = fmaf(a.w,w3,acc0);
            acc1 = fmaf(b4.x,w0,acc1); acc1 = fmaf(b4.y,w1,acc1);
            acc1 = fmaf(b4.z,w2,acc1); acc1 = fmaf(b4.w,w3,acc1);
          }
          rin[(size_t)(b0+bg  )*RC + j] = acc0;
          rin[(size_t)(b0+bg+4)*RC + j] = acc1;
        }
      }
    } else {
      if (tid < 64) {
        int cl = tid & 15, bg = tid >> 4;
        int col = js*16 + cl;
        float acc0 = bl[col], acc1 = acc0;
        const float* w = W1c + col;
        const float4* x4a = (const float4*)(&xls[bg][0]);
        const float4* x4b = (const float4*)(&xls[bg+4][0]);
        #pragma unroll 4
        for (int k4 = 0; k4 < XK/4; ++k4) {
          float4 a = x4a[k4], b4 = x4b[k4];
          float w0 = w[0], w1 = w[GC], w2 = w[2*GC], w3 = w[3*GC];
          w += 4*GC;
          acc0 = fmaf(a.x,w0,acc0);  acc0 = fmaf(a.y,w1,acc0);
          acc0 = fmaf(a.z,w2,acc0);  acc0 = fmaf(a.w,w3,acc0);
          acc1 = fmaf(b4.x,w0,acc1); acc1 = fmaf(b4.y,w1,acc1);
          acc1 = fmaf(b4.z,w2,acc1); acc1 = fmaf(b4.w,w3,acc1);
        }
        gcur[(b0+bg  )*GC + col] = acc0;
        gcur[(b0+bg+4)*GC + col] = acc1;
      }
    }

    gbar(cnt, (++nbar)*NWG);

    if (red) {
      // ---- I2: LSTM, finish r_in with h@Wtrack, reduce cell, stack write ----
      lstm_apply(gcur, chs, b0, tid);
      __syncthreads();
      for (int it = tid; it < BBR*16; it += MBLK) {
        int r = it >> 4, ul = it & 15;
        if (!shf[r]) {
          int u = js*16 + ul;
          int b = b0 + r;
          int sp = spb[r];
          const float* rb = rin + (size_t)b*RC;
          float v0 = rb[u], v1 = rb[256+u], v2 = rb[512+u], v3 = rb[768+u], v4 = rb[1024+u];
          const float* wt = Wtrack + u;
          #pragma unroll 4
          for (int k = 0; k < KDIM; ++k) {
            float hv = chs[r][KDIM + k];
            const float* w = wt + (size_t)k*RC;
            v0 = fmaf(hv, w[0],    v0);
            v1 = fmaf(hv, w[256],  v1);
            v2 = fmaf(hv, w[512],  v2);
            v3 = fmaf(hv, w[768],  v3);
            v4 = fmaf(hv, w[1024], v4);
          }
          float s1c = (sp >= 1) ? stack[((size_t)b*(SEQN+1) + sp-1)*TWOH + HDIM + u] : 0.0f;
          float s2c = (sp >= 2) ? stack[((size_t)b*(SEQN+1) + sp-2)*TWOH + HDIM + u] : 0.0f;
          float cred = tanh_s(v0)*sigm(v1) + sigm(v2)*s2c + sigm(v3)*s1c;
          float hred = sigm(v4)*tanh_s(cred);
          int wp = sp - 2; if (wp < 0) wp = 0;
          float* dst = stack + ((size_t)b*(SEQN+1) + wp)*TWOH;
          dst[u]        = hred;
          dst[HDIM + u] = cred;
        }
      }
      __syncthreads();
      if (tid < BBR) {
        spb[tid] += shf[tid] ? 1 : -1;
        bpb[tid] += shf[tid] ? 1 : 0;
      }
      pending = 0;
      gbar(cnt, (++nbar)*NWG);
    } else {
      if (tid < BBR) { spb[tid] += 1; bpb[tid] += 1; }
      pending = 1;
    }
  }
}

// ---------------- epilogue MLP ----------------
__global__ __launch_bounds__(256) void epi_kernel(
    const int* __restrict__ trans, const float* __restrict__ stack,
    const float* __restrict__ W1, const float* __restrict__ b1,
    const float* __restrict__ W2, const float* __restrict__ b2,
    float* __restrict__ out)
{
  __shared__ float top[HDIM];
  __shared__ float hid[MDIM];
  __shared__ float redbuf[256];
  __shared__ int spf_s;
  int b = blockIdx.x, tid = threadIdx.x;
  if (tid == 0) {
    int sp = 0;
    for (int t = 0; t < NSTEP; ++t) sp += (trans[b*NSTEP + t] == 0) ? 1 : -1;
    spf_s = (sp - 1) > 0 ? (sp - 1) : 0;
  }
  __syncthreads();
  int spf = spf_s;
  for (int c = tid; c < HDIM; c += 256)
    top[c] = stack[((size_t)b*(SEQN+1) + spf)*TWOH + c];
  __syncthreads();
  for (int j = tid; j < MDIM; j += 256) {
    float acc = b1[j];
    for (int k = 0; k < HDIM; ++k) acc = fmaf(top[k], W1[(size_t)k*MDIM + j], acc);
    hid[j] = fmaxf(acc, 0.0f);
  }
  __syncthreads();
  for (int c = 0; c < COUT; ++c) {
    float p = 0.0f;
    for (int k = tid; k < MDIM; k += 256) p = fmaf(hid[k], W2[(size_t)k*COUT + c], p);
    redbuf[tid] = p; __syncthreads();
    for (int off = 128; off > 0; off >>= 1) {
      if (tid < off) redbuf[tid] += redbuf[tid + off];
      __syncthreads();
    }
    if (tid == 0) out[b*COUT + c] = redbuf[0] + b2[c];
    __syncthreads();
  }
}

extern "C" void kernel_launch(void* const* d_in, const int* in_sizes, int n_in,
                              void* d_out, int out_size, void* d_ws, size_t ws_size,
                              hipStream_t stream)
{
  const int*   tokens = (const int*)  d_in[0];
  const int*   trans  = (const int*)  d_in[1];
  const float* emb    = (const float*)d_in[2];
  const float* Wproj  = (const float*)d_in[3];
  const float* Wl     = (const float*)d_in[4];
  const float* blp    = (const float*)d_in[5];
  const float* Wb     = (const float*)d_in[6];
  const float* Ws1    = (const float*)d_in[7];
  const float* Ws2    = (const float*)d_in[8];
  const float* Wleft  = (const float*)d_in[9];
  const float* Wright = (const float*)d_in[10];
  const float* Wtr    = (const float*)d_in[11];
  const float* bred   = (const float*)d_in[12];
  const float* W1     = (const float*)d_in[13];
  const float* b1     = (const float*)d_in[14];
  const float* W2     = (const float*)d_in[15];
  const float* b2     = (const float*)d_in[16];
  float* out = (float*)d_out;
  float* ws  = (float*)d_ws;

  float* bufs   = ws + OFF_BUFS;
  float* stack  = ws + OFF_STACK;
  float* gatesg = ws + OFF_GATES;
  float* rin    = ws + OFF_RIN;
  float* W1c    = ws + OFF_W1;
  float* W2c    = ws + OFF_W2;
  int*   ints   = (int*)(ws + OFF_END);
  int*   anyred = ints;
  int*   cnt    = ints + 256;

  pack_kernel<<<dim3(512), dim3(256), 0, stream>>>(Wb, Ws1, Ws2, Wl, Wleft, Wright,
                                                   trans, W1c, W2c, anyred, cnt);
  embed_kernel<<<dim3((BATCH*SEQN)/4), dim3(256), 0, stream>>>(tokens, emb, Wproj, bufs);
  spinn_main<<<dim3(NWG), dim3(MBLK), 0, stream>>>(trans, Wtr, blp, bred, bufs, stack,
                                                   gatesg, rin, W1c, W2c, anyred, cnt);
  epi_kernel<<<dim3(BATCH), dim3(256), 0, stream>>>(trans, stack, W1, b1, W2, b2, out);
}

// Round 2
// 7692.346 us; speedup vs baseline: 5.5365x; 5.5365x over previous
//
#include <hip/hip_runtime.h>

#define BATCH 128
#define SEQN  128
#define NSTEP 255          // 2N-1
#define HDIM  256
#define KDIM  64
#define EDIM  300
#define MDIM  1024
#define COUT  3
#define TWOH  512
#define GC    256          // gates cols (4K)
#define RC    1280         // r_in cols (5H)
#define XK    832          // [bufH | s1H | s2H | h] = 256+256+256+64
#define RK    512          // [s1H | s2H]

#define NWG   256
#define MBLK  512
#define BBR   8            // batch rows per b-block; 16 b-blocks * 8 = 128
#define FPAD  4            // ints between barrier flags

// ---- workspace float offsets ----
constexpr size_t OFF_BUFS  = 0;
constexpr size_t SZ_BUFS   = (size_t)BATCH*SEQN*TWOH;          // 8388608
constexpr size_t OFF_STACK = OFF_BUFS + SZ_BUFS;
constexpr size_t SZ_STACK  = (size_t)BATCH*(SEQN+1)*TWOH;      // 8454144
constexpr size_t OFF_GATES = OFF_STACK + SZ_STACK;
constexpr size_t SZ_GATES  = (size_t)2*BATCH*GC;               // double-buffered
constexpr size_t OFF_RIN   = OFF_GATES + SZ_GATES;
constexpr size_t SZ_RIN    = (size_t)BATCH*RC;
constexpr size_t OFF_W1    = OFF_RIN + SZ_RIN;
constexpr size_t SZ_W1     = (size_t)XK*GC;                    // [Wb;Ws1;Ws2;Wl]
constexpr size_t OFF_W2    = OFF_W1 + SZ_W1;
constexpr size_t SZ_W2     = (size_t)RK*RC;                    // [Wright;Wleft]
constexpr size_t OFF_END   = OFF_W2 + SZ_W2;
// int area (after OFF_END floats): anyred[256], then flags[NWG*FPAD], bcast[8]
constexpr int INT_ANYRED = 0;
constexpr int INT_FLAGS  = 256;
constexpr int INT_BCAST  = 256 + NWG*FPAD;
constexpr int INT_TOTAL  = INT_BCAST + 8;

__device__ __forceinline__ float sigm(float x) { return 1.0f/(1.0f + __expf(-x)); }
__device__ __forceinline__ float tanh_s(float x) {
  float a = fabsf(x);
  float e = __expf(-2.0f*a);
  float t = (1.0f - e)/(1.0f + e);
  return x < 0.0f ? -t : t;
}

// ---- relaxed agent-scope (cache-bypassing, no fence) accessors for cross-WG data ----
__device__ __forceinline__ float gld(const float* p) {
  return __hip_atomic_load(p, __ATOMIC_RELAXED, __HIP_MEMORY_SCOPE_AGENT);
}
__device__ __forceinline__ void gst(float* p, float v) {
  __hip_atomic_store(p, v, __ATOMIC_RELAXED, __HIP_MEMORY_SCOPE_AGENT);
}
__device__ __forceinline__ int ild(const int* p) {
  return __hip_atomic_load(p, __ATOMIC_RELAXED, __HIP_MEMORY_SCOPE_AGENT);
}
__device__ __forceinline__ void ist(int* p, int v) {
  __hip_atomic_store(p, v, __ATOMIC_RELAXED, __HIP_MEMORY_SCOPE_AGENT);
}

// ---------------- pack: concat weights, any_reduce flags, zero barrier state ----------------
__global__ __launch_bounds__(256) void pack_kernel(
    const float* __restrict__ Wb, const float* __restrict__ Ws1,
    const float* __restrict__ Ws2, const float* __restrict__ Wl,
    const float* __restrict__ Wleft, const float* __restrict__ Wright,
    const int* __restrict__ trans,
    float* __restrict__ W1c, float* __restrict__ W2c,
    int* __restrict__ ints)
{
  int gs = gridDim.x * blockDim.x;
  int t0 = blockIdx.x*blockDim.x + threadIdx.x;
  for (int i = t0; i < XK*GC; i += gs) {
    int k = i / GC, j = i - k*GC;
    float v;
    if (k < 256)      v = Wb [(k      )*GC + j];
    else if (k < 512) v = Ws1[(k-256  )*GC + j];
    else if (k < 768) v = Ws2[(k-512  )*GC + j];
    else              v = Wl [(k-768  )*GC + j];
    W1c[i] = v;
  }
  for (int i = t0; i < RK*RC; i += gs) {
    int k = i / RC, j = i - k*RC;
    W2c[i] = (k < 256) ? Wright[k*RC + j] : Wleft[(k-256)*RC + j];
  }
  for (int i = t0; i < NSTEP; i += gs) {
    int any = 0;
    for (int b = 0; b < BATCH; ++b) any |= (trans[b*NSTEP + i] != 0);
    ints[INT_ANYRED + i] = any;
  }
  // zero barrier flags + broadcast through the same bypass path the scan uses
  for (int i = t0; i < INT_TOTAL - INT_FLAGS; i += gs) {
    ist(&ints[INT_FLAGS + i], 0);
  }
}

// ---------------- embedding + projection: bufs[b][n][:] = emb[tok] @ Wproj ----------------
__global__ __launch_bounds__(256) void embed_kernel(
    const int* __restrict__ tokens, const float* __restrict__ emb,
    const float* __restrict__ Wproj, float* __restrict__ bufs)
{
  __shared__ float xe[4][EDIM];
  int r0 = blockIdx.x * 4;
  int tid = threadIdx.x;
  for (int i = tid; i < 4*EDIM; i += 256) {
    int r = i / EDIM, e = i - r*EDIM;
    xe[r][e] = emb[(size_t)tokens[r0 + r]*EDIM + e];
  }
  __syncthreads();
  int c0 = tid*2;
  float a00=0,a01=0,a10=0,a11=0,a20=0,a21=0,a30=0,a31=0;
  for (int e = 0; e < EDIM; ++e) {
    float2 w = *(const float2*)(Wproj + (size_t)e*TWOH + c0);
    float x0 = xe[0][e], x1 = xe[1][e], x2 = xe[2][e], x3 = xe[3][e];
    a00 = fmaf(x0, w.x, a00); a01 = fmaf(x0, w.y, a01);
    a10 = fmaf(x1, w.x, a10); a11 = fmaf(x1, w.y, a11);
    a20 = fmaf(x2, w.x, a20); a21 = fmaf(x2, w.y, a21);
    a30 = fmaf(x3, w.x, a30); a31 = fmaf(x3, w.y, a31);
  }
  float* o;
  o = bufs + (size_t)(r0+0)*TWOH + c0; o[0]=a00; o[1]=a01;
  o = bufs + (size_t)(r0+1)*TWOH + c0; o[0]=a10; o[1]=a11;
  o = bufs + (size_t)(r0+2)*TWOH + c0; o[0]=a20; o[1]=a21;
  o = bufs + (size_t)(r0+3)*TWOH + c0; o[0]=a30; o[1]=a31;
}

// ---------------- contention-free grid barrier (no acquire fences, no RMW) ----------------
// Producer order: __syncthreads() drains each wave's stores (compiler emits vmcnt(0)
// before s_barrier; we add an explicit one for insurance), THEN tid0 publishes the flag.
// All cross-WG data moves via relaxed agent-scope atomics (memory-side coherence point),
// so no cache invalidation is ever required on the consumer side.
__device__ __forceinline__ void gbar(int* flags, int* bcast, int epoch)
{
  asm volatile("s_waitcnt vmcnt(0)" ::: "memory");
  __syncthreads();
  if (blockIdx.x == 0) {
    if (threadIdx.x == 0) ist(&flags[0], epoch);
    if (threadIdx.x < NWG) {
      while (ild(&flags[threadIdx.x*FPAD]) < epoch) __builtin_amdgcn_s_sleep(2);
    }
    __syncthreads();
    if (threadIdx.x == 0) ist(bcast, epoch);
  } else {
    if (threadIdx.x == 0) {
      ist(&flags[blockIdx.x*FPAD], epoch);
      while (ild(bcast) < epoch) __builtin_amdgcn_s_sleep(2);
    }
    __syncthreads();
  }
}

__device__ __forceinline__ void lstm_apply(const float* __restrict__ g,
                                           float (*chs)[2*KDIM], int b0, int tid)
{
  for (int it = tid; it < BBR*KDIM; it += MBLK) {
    int r = it >> 6, u = it & 63;
    const float* gr = g + (b0 + r)*GC;
    float cprev = chs[r][u];
    float ga = gld(gr + u), gi = gld(gr + 64 + u), gf = gld(gr + 128 + u), go = gld(gr + 192 + u);
    float cc = tanh_s(ga)*sigm(gi) + sigm(gf)*cprev;
    chs[r][u] = cc;
    chs[r][KDIM+u] = sigm(go)*tanh_s(cc);
  }
}

__global__ __launch_bounds__(MBLK) void spinn_main(
    const int* __restrict__ trans,
    const float* __restrict__ Wtrack,
    const float* __restrict__ bl,
    const float* __restrict__ bred,
    const float* __restrict__ bufs,
    float* __restrict__ stack,
    float* __restrict__ gatesg,
    float* __restrict__ rin,
    const float* __restrict__ W1c,
    const float* __restrict__ W2c,
    int* __restrict__ ints)
{
  __shared__ __align__(16) float xls[BBR][XK];
  __shared__ float chs[BBR][2*KDIM];     // [r][0:64)=c, [r][64:128)=h
  __shared__ int spb[BBR], bpb[BBR], shf[BBR];
  __shared__ int anyr[NSTEP];

  const int tid = threadIdx.x;
  const int wg  = blockIdx.x;
  const int bb  = wg >> 4;
  const int js  = wg & 15;
  const int b0  = bb * BBR;

  int* flags = ints + INT_FLAGS;
  int* bcast = ints + INT_BCAST;

  for (int i = tid; i < BBR*2*KDIM; i += MBLK) ((float*)chs)[i] = 0.0f;
  if (tid < BBR) { spb[tid] = 0; bpb[tid] = 0; }
  for (int i = tid; i < NSTEP; i += MBLK) anyr[i] = ints[INT_ANYRED + i];
  __syncthreads();

  int nbar = 0;
  int pending = 0;

  for (int t = 0; t < NSTEP; ++t) {
    const int red = anyr[t];
    float* gcur        = gatesg + (size_t)(t & 1)*(BATCH*GC);
    const float* gprev = gatesg + (size_t)((t & 1)^1)*(BATCH*GC);

    if (pending) lstm_apply(gprev, chs, b0, tid);   // LSTM of step t-1 (shift step)
    if (tid < BBR) shf[tid] = (trans[(b0+tid)*NSTEP + t] == 0) ? 1 : 0;
    __syncthreads();

    // ---- stage x = [bufH | s1H | s2H | h] into LDS ----
    for (int idx = tid; idx < BBR*HDIM; idx += MBLK) {
      int r = idx >> 8, c = idx & (HDIM-1);
      int b = b0 + r;
      int sp = spb[r], bp = bpb[r];
      int bq = bp < SEQN-1 ? bp : SEQN-1;
      xls[r][c]          = bufs[((size_t)b*SEQN + bq)*TWOH + c];
      xls[r][HDIM + c]   = (sp >= 1) ? gld(&stack[((size_t)b*(SEQN+1) + sp-1)*TWOH + c]) : 0.0f;
      xls[r][2*HDIM + c] = (sp >= 2) ? gld(&stack[((size_t)b*(SEQN+1) + sp-2)*TWOH + c]) : 0.0f;
    }
    for (int it = tid; it < BBR*KDIM; it += MBLK) {
      int r = it >> 6, u = it & 63;
      xls[r][3*HDIM + u] = chs[r][KDIM + u];
    }
    __syncthreads();

    // ---- shift-row stack pushes (value is buf_top; no GEMM needed) ----
    if (js == 0) {
      for (int idx = tid; idx < BBR*TWOH; idx += MBLK) {
        int r = idx >> 9, c = idx & (TWOH-1);
        if (shf[r]) {
          int b = b0 + r;
          int bq = bpb[r] < SEQN-1 ? bpb[r] : SEQN-1;
          gst(&stack[((size_t)b*(SEQN+1) + spb[r])*TWOH + c],
              bufs[((size_t)b*SEQN + bq)*TWOH + c]);
        }
      }
    }

    // ---- I1 compute: gates (and r_in s-part on reduce steps) ----
    if (red) {
      for (int s = tid; s < 384; s += MBLK) {
        int cl = s % 96, bg = s / 96;
        int col = js*96 + cl;
        const float* xa = &xls[bg][0];
        const float* xb = &xls[bg+4][0];
        if (col < GC) {
          float acc0 = bl[col], acc1 = acc0;
          const float* w = W1c + col;
          const float4* x4a = (const float4*)xa;
          const float4* x4b = (const float4*)xb;
          #pragma unroll 4
          for (int k4 = 0; k4 < XK/4; ++k4) {
            float4 a = x4a[k4], b4 = x4b[k4];
            float w0 = w[0], w1 = w[GC], w2 = w[2*GC], w3 = w[3*GC];
            w += 4*GC;
            acc0 = fmaf(a.x,w0,acc0);  acc0 = fmaf(a.y,w1,acc0);
            acc0 = fmaf(a.z,w2,acc0);  acc0 = fmaf(a.w,w3,acc0);
            acc1 = fmaf(b4.x,w0,acc1); acc1 = fmaf(b4.y,w1,acc1);
            acc1 = fmaf(b4.z,w2,acc1); acc1 = fmaf(b4.w,w3,acc1);
          }
          gst(&gcur[(b0+bg  )*GC + col], acc0);
          gst(&gcur[(b0+bg+4)*GC + col], acc1);
        } else {
          int j = col - GC;
          float acc0 = bred[j], acc1 = acc0;
          const float* w = W2c + j;
          const float4* x4a = (const float4*)(xa + HDIM);   // [s1H | s2H]
          const float4* x4b = (const float4*)(xb + HDIM);
          #pragma unroll 4
          for (int k4 = 0; k4 < RK/4; ++k4) {
            float4 a = x4a[k4], b4 = x4b[k4];
            float w0 = w[0], w1 = w[RC], w2 = w[2*RC], w3 = w[3*RC];
            w += 4*RC;
            acc0 = fmaf(a.x,w0,acc0);  acc0 = fmaf(a.y,w1,acc0);
            acc0 = fmaf(a.z,w2,acc0);  acc0 = fmaf(a.w,w3,acc0);
            acc1 = fmaf(b4.x,w0,acc1); acc1 = fmaf(b4.y,w1,acc1);
            acc1 = fmaf(b4.z,w2,acc1); acc1 = fmaf(b4.w,w3,acc1);
          }
          gst(&rin[(size_t)(b0+bg  )*RC + j], acc0);
          gst(&rin[(size_t)(b0+bg+4)*RC + j], acc1);
        }
      }
    } else {
      if (tid < 64) {
        int cl = tid & 15, bg = tid >> 4;
        int col = js*16 + cl;
        float acc0 = bl[col], acc1 = acc0;
        const float* w = W1c + col;
        const float4* x4a = (const float4*)(&xls[bg][0]);
        const float4* x4b = (const float4*)(&xls[bg+4][0]);
        #pragma unroll 4
        for (int k4 = 0; k4 < XK/4; ++k4) {
          float4 a = x4a[k4], b4 = x4b[k4];
          float w0 = w[0], w1 = w[GC], w2 = w[2*GC], w3 = w[3*GC];
          w += 4*GC;
          acc0 = fmaf(a.x,w0,acc0);  acc0 = fmaf(a.y,w1,acc0);
          acc0 = fmaf(a.z,w2,acc0);  acc0 = fmaf(a.w,w3,acc0);
          acc1 = fmaf(b4.x,w0,acc1); acc1 = fmaf(b4.y,w1,acc1);
          acc1 = fmaf(b4.z,w2,acc1); acc1 = fmaf(b4.w,w3,acc1);
        }
        gst(&gcur[(b0+bg  )*GC + col], acc0);
        gst(&gcur[(b0+bg+4)*GC + col], acc1);
      }
    }

    gbar(flags, bcast, ++nbar);

    if (red) {
      // ---- I2: LSTM, finish r_in with h@Wtrack, reduce cell, stack write ----
      lstm_apply(gcur, chs, b0, tid);
      __syncthreads();
      for (int it = tid; it < BBR*16; it += MBLK) {
        int r = it >> 4, ul = it & 15;
        if (!shf[r]) {
          int u = js*16 + ul;
          int b = b0 + r;
          int sp = spb[r];
          const float* rb = rin + (size_t)b*RC;
          float v0 = gld(rb + u), v1 = gld(rb + 256+u), v2 = gld(rb + 512+u),
                v3 = gld(rb + 768+u), v4 = gld(rb + 1024+u);
          const float* wt = Wtrack + u;
          #pragma unroll 4
          for (int k = 0; k < KDIM; ++k) {
            float hv = chs[r][KDIM + k];
            const float* w = wt + (size_t)k*RC;
            v0 = fmaf(hv, w[0],    v0);
            v1 = fmaf(hv, w[256],  v1);
            v2 = fmaf(hv, w[512],  v2);
            v3 = fmaf(hv, w[768],  v3);
            v4 = fmaf(hv, w[1024], v4);
          }
          float s1c = (sp >= 1) ? gld(&stack[((size_t)b*(SEQN+1) + sp-1)*TWOH + HDIM + u]) : 0.0f;
          float s2c = (sp >= 2) ? gld(&stack[((size_t)b*(SEQN+1) + sp-2)*TWOH + HDIM + u]) : 0.0f;
          float cred = tanh_s(v0)*sigm(v1) + sigm(v2)*s2c + sigm(v3)*s1c;
          float hred = sigm(v4)*tanh_s(cred);
          int wp = sp - 2; if (wp < 0) wp = 0;
          float* dst = stack + ((size_t)b*(SEQN+1) + wp)*TWOH;
          gst(dst + u,        hred);
          gst(dst + HDIM + u, cred);
        }
      }
      __syncthreads();
      if (tid < BBR) {
        spb[tid] += shf[tid] ? 1 : -1;
        bpb[tid] += shf[tid] ? 1 : 0;
      }
      pending = 0;
      gbar(flags, bcast, ++nbar);
    } else {
      if (tid < BBR) { spb[tid] += 1; bpb[tid] += 1; }
      pending = 1;
    }
  }
}

// ---------------- epilogue MLP ----------------
__global__ __launch_bounds__(256) void epi_kernel(
    const int* __restrict__ trans, const float* __restrict__ stack,
    const float* __restrict__ W1, const float* __restrict__ b1,
    const float* __restrict__ W2, const float* __restrict__ b2,
    float* __restrict__ out)
{
  __shared__ float top[HDIM];
  __shared__ float hid[MDIM];
  __shared__ float redbuf[256];
  __shared__ int spf_s;
  int b = blockIdx.x, tid = threadIdx.x;
  if (tid == 0) {
    int sp = 0;
    for (int t = 0; t < NSTEP; ++t) sp += (trans[b*NSTEP + t] == 0) ? 1 : -1;
    spf_s = (sp - 1) > 0 ? (sp - 1) : 0;
  }
  __syncthreads();
  int spf = spf_s;
  for (int c = tid; c < HDIM; c += 256)
    top[c] = stack[((size_t)b*(SEQN+1) + spf)*TWOH + c];
  __syncthreads();
  for (int j = tid; j < MDIM; j += 256) {
    float acc = b1[j];
    for (int k = 0; k < HDIM; ++k) acc = fmaf(top[k], W1[(size_t)k*MDIM + j], acc);
    hid[j] = fmaxf(acc, 0.0f);
  }
  __syncthreads();
  for (int c = 0; c < COUT; ++c) {
    float p = 0.0f;
    for (int k = tid; k < MDIM; k += 256) p = fmaf(hid[k], W2[(size_t)k*COUT + c], p);
    redbuf[tid] = p; __syncthreads();
    for (int off = 128; off > 0; off >>= 1) {
      if (tid < off) redbuf[tid] += redbuf[tid + off];
      __syncthreads();
    }
    if (tid == 0) out[b*COUT + c] = redbuf[0] + b2[c];
    __syncthreads();
  }
}

extern "C" void kernel_launch(void* const* d_in, const int* in_sizes, int n_in,
                              void* d_out, int out_size, void* d_ws, size_t ws_size,
                              hipStream_t stream)
{
  const int*   tokens = (const int*)  d_in[0];
  const int*   trans  = (const int*)  d_in[1];
  const float* emb    = (const float*)d_in[2];
  const float* Wproj  = (const float*)d_in[3];
  const float* Wl     = (const float*)d_in[4];
  const float* blp    = (const float*)d_in[5];
  const float* Wb     = (const float*)d_in[6];
  const float* Ws1    = (const float*)d_in[7];
  const float* Ws2    = (const float*)d_in[8];
  const float* Wleft  = (const float*)d_in[9];
  const float* Wright = (const float*)d_in[10];
  const float* Wtr    = (const float*)d_in[11];
  const float* bred   = (const float*)d_in[12];
  const float* W1     = (const float*)d_in[13];
  const float* b1     = (const float*)d_in[14];
  const float* W2     = (const float*)d_in[15];
  const float* b2     = (const float*)d_in[16];
  float* out = (float*)d_out;
  float* ws  = (float*)d_ws;

  float* bufs   = ws + OFF_BUFS;
  float* stack  = ws + OFF_STACK;
  float* gatesg = ws + OFF_GATES;
  float* rin    = ws + OFF_RIN;
  float* W1c    = ws + OFF_W1;
  float* W2c    = ws + OFF_W2;
  int*   ints   = (int*)(ws + OFF_END);

  pack_kernel<<<dim3(512), dim3(256), 0, stream>>>(Wb, Ws1, Ws2, Wl, Wleft, Wright,
                                                   trans, W1c, W2c, ints);
  embed_kernel<<<dim3((BATCH*SEQN)/4), dim3(256), 0, stream>>>(tokens, emb, Wproj, bufs);
  spinn_main<<<dim3(NWG), dim3(MBLK), 0, stream>>>(trans, Wtr, blp, bred, bufs, stack,
                                                   gatesg, rin, W1c, W2c, ints);
  epi_kernel<<<dim3(BATCH), dim3(256), 0, stream>>>(trans, stack, W1, b1, W2, b2, out);
}